// Round 1
// baseline (926.386 us; speedup 1.0000x reference)
//
#include <hip/hip_runtime.h>

#define F_IN  512
#define F_OUT 128

// ---------------------------------------------------------------------------
// GEMM: h[N,128] = x[N,512] @ w[512,128], fp32.
// 64x128 tile per 256-thread block, BK=16. Each thread: 8 rows x 4 cols.
// LDS x-tile stored transposed [k][row] (stride 68 keeps float4 alignment),
// w-tile [k][col] (stride 132). 2 FMAs per LDS-word read.
// ---------------------------------------------------------------------------
__global__ __launch_bounds__(256, 2) void gemm64x128(
    const float* __restrict__ x, const float* __restrict__ w,
    float* __restrict__ h, int N)
{
    __shared__ float sx[16][68];    // [k][row], 68 = 64 + 4 pad (16B-aligned rows)
    __shared__ float sw[16][132];   // [k][col], 132 = 128 + 4 pad

    const int tid  = threadIdx.x;
    const int n0   = blockIdx.x * 64;
    const int tx   = tid & 31;      // col group: cols tx*4 .. tx*4+3
    const int ty   = tid >> 5;      // row group: rows ty*8 .. ty*8+7
    const int xrow = tid >> 2;      // 0..63  (x staging)
    const int xkv  = (tid & 3) * 4; // 0,4,8,12
    const int wrow = tid >> 5;      // 0..7   (w staging)
    const int wcol = (tid & 31) * 4;

    float acc[8][4];
    #pragma unroll
    for (int i = 0; i < 8; ++i)
        #pragma unroll
        for (int j = 0; j < 4; ++j) acc[i][j] = 0.f;

    const int  nrow   = n0 + xrow;
    const bool xvalid = nrow < N;

    for (int k0 = 0; k0 < F_IN; k0 += 16) {
        // global loads for this tile (before barrier so they overlap compute)
        float4 xv = make_float4(0.f, 0.f, 0.f, 0.f);
        if (xvalid) xv = *(const float4*)&x[(size_t)nrow * F_IN + k0 + xkv];
        float4 wv0 = *(const float4*)&w[(size_t)(k0 + wrow    ) * F_OUT + wcol];
        float4 wv1 = *(const float4*)&w[(size_t)(k0 + wrow + 8) * F_OUT + wcol];

        __syncthreads();   // previous tile's compute done before overwrite
        sx[xkv + 0][xrow] = xv.x;
        sx[xkv + 1][xrow] = xv.y;
        sx[xkv + 2][xrow] = xv.z;
        sx[xkv + 3][xrow] = xv.w;
        *(float4*)&sw[wrow    ][wcol] = wv0;
        *(float4*)&sw[wrow + 8][wcol] = wv1;
        __syncthreads();

        #pragma unroll
        for (int k = 0; k < 16; ++k) {
            float a[8];
            *(float4*)&a[0] = *(const float4*)&sx[k][ty * 8];
            *(float4*)&a[4] = *(const float4*)&sx[k][ty * 8 + 4];
            float4 b = *(const float4*)&sw[k][tx * 4];
            #pragma unroll
            for (int i = 0; i < 8; ++i) {
                acc[i][0] += a[i] * b.x;
                acc[i][1] += a[i] * b.y;
                acc[i][2] += a[i] * b.z;
                acc[i][3] += a[i] * b.w;
            }
        }
    }

    #pragma unroll
    for (int i = 0; i < 8; ++i) {
        int r = n0 + ty * 8 + i;
        if (r < N) *(float4*)&h[(size_t)r * F_OUT + tx * 4] = *(float4*)&acc[i][0];
    }
}

// ---------------------------------------------------------------------------
// Scatter: out[dst] += h[src] * w_e  via fp32 global atomics.
// One thread per (edge, feature). 256-thread block = 2 edges.
// Wave of 64 lanes covers half a feature row -> coalesced gather + atomic.
// ---------------------------------------------------------------------------
__global__ __launch_bounds__(256) void scatter_atomic(
    const float* __restrict__ h, const int* __restrict__ ei,
    const float* __restrict__ ew, float* __restrict__ out, int E)
{
    long long gid = (long long)blockIdx.x * 256 + threadIdx.x;
    int e = (int)(gid >> 7);        // edge index
    int f = (int)(gid & 127);       // feature index
    if (e >= E) return;
    int   src = ei[e];              // edge_index[0][e]
    int   dst = ei[E + e];          // edge_index[1][e]
    float wgt = ew[e];
    float v   = h[(size_t)src * F_OUT + f] * wgt;
    atomicAdd(&out[(size_t)dst * F_OUT + f], v);
}

// ---------------------------------------------------------------------------
// Epilogue: out = relu(out + bias), vectorized float4.
// ---------------------------------------------------------------------------
__global__ __launch_bounds__(256) void epilogue_bias_relu(
    float* __restrict__ out, const float* __restrict__ bias, int total)
{
    int i4 = (blockIdx.x * 256 + threadIdx.x) * 4;
    if (i4 >= total) return;
    float4 v = *(float4*)&out[i4];
    float4 b = *(const float4*)&bias[i4 & 127];   // col = i4 % 128, 16B aligned
    v.x = fmaxf(v.x + b.x, 0.f);
    v.y = fmaxf(v.y + b.y, 0.f);
    v.z = fmaxf(v.z + b.z, 0.f);
    v.w = fmaxf(v.w + b.w, 0.f);
    *(float4*)&out[i4] = v;
}

extern "C" void kernel_launch(void* const* d_in, const int* in_sizes, int n_in,
                              void* d_out, int out_size, void* d_ws, size_t ws_size,
                              hipStream_t stream)
{
    const float* x    = (const float*)d_in[0];   // [N, 512]
    const int*   ei   = (const int*)  d_in[1];   // [2, E] int32
    const float* ew   = (const float*)d_in[2];   // [E]
    const float* w    = (const float*)d_in[3];   // [512, 128]
    const float* bias = (const float*)d_in[4];   // [128]
    float*       out  = (float*)d_out;           // [N, 128]
    float*       h    = (float*)d_ws;            // [N, 128] scratch (25.6 MB)

    const int N = in_sizes[0] / F_IN;            // 50000
    const int E = in_sizes[2];                   // 1600000 (edge_weight count)

    // out is poisoned 0xAA every call — zero it for the atomic accumulation
    hipMemsetAsync(d_out, 0, (size_t)out_size * sizeof(float), stream);

    gemm64x128<<<(N + 63) / 64, 256, 0, stream>>>(x, w, h, N);

    long long work = (long long)E * F_OUT;
    int sblocks = (int)((work + 255) / 256);
    scatter_atomic<<<sblocks, 256, 0, stream>>>(h, ei, ew, out, E);

    int total = N * F_OUT;
    epilogue_bias_relu<<<(total / 4 + 255) / 256, 256, 0, stream>>>(out, bias, total);
}

// Round 2
// 537.100 us; speedup vs baseline: 1.7248x; 1.7248x over previous
//
#include <hip/hip_runtime.h>

#define F_IN  512
#define F_OUT 128

// ---------------------------------------------------------------------------
// GEMM: h[N,128] = x[N,512] @ w[512,128], fp32 (unchanged from R1).
// ---------------------------------------------------------------------------
__global__ __launch_bounds__(256, 2) void gemm64x128(
    const float* __restrict__ x, const float* __restrict__ w,
    float* __restrict__ h, int N)
{
    __shared__ float sx[16][68];
    __shared__ float sw[16][132];

    const int tid  = threadIdx.x;
    const int n0   = blockIdx.x * 64;
    const int tx   = tid & 31;
    const int ty   = tid >> 5;
    const int xrow = tid >> 2;
    const int xkv  = (tid & 3) * 4;
    const int wrow = tid >> 5;
    const int wcol = (tid & 31) * 4;

    float acc[8][4];
    #pragma unroll
    for (int i = 0; i < 8; ++i)
        #pragma unroll
        for (int j = 0; j < 4; ++j) acc[i][j] = 0.f;

    const int  nrow   = n0 + xrow;
    const bool xvalid = nrow < N;

    for (int k0 = 0; k0 < F_IN; k0 += 16) {
        float4 xv = make_float4(0.f, 0.f, 0.f, 0.f);
        if (xvalid) xv = *(const float4*)&x[(size_t)nrow * F_IN + k0 + xkv];
        float4 wv0 = *(const float4*)&w[(size_t)(k0 + wrow    ) * F_OUT + wcol];
        float4 wv1 = *(const float4*)&w[(size_t)(k0 + wrow + 8) * F_OUT + wcol];

        __syncthreads();
        sx[xkv + 0][xrow] = xv.x;
        sx[xkv + 1][xrow] = xv.y;
        sx[xkv + 2][xrow] = xv.z;
        sx[xkv + 3][xrow] = xv.w;
        *(float4*)&sw[wrow    ][wcol] = wv0;
        *(float4*)&sw[wrow + 8][wcol] = wv1;
        __syncthreads();

        #pragma unroll
        for (int k = 0; k < 16; ++k) {
            float a[8];
            *(float4*)&a[0] = *(const float4*)&sx[k][ty * 8];
            *(float4*)&a[4] = *(const float4*)&sx[k][ty * 8 + 4];
            float4 b = *(const float4*)&sw[k][tx * 4];
            #pragma unroll
            for (int i = 0; i < 8; ++i) {
                acc[i][0] += a[i] * b.x;
                acc[i][1] += a[i] * b.y;
                acc[i][2] += a[i] * b.z;
                acc[i][3] += a[i] * b.w;
            }
        }
    }

    #pragma unroll
    for (int i = 0; i < 8; ++i) {
        int r = n0 + ty * 8 + i;
        if (r < N) *(float4*)&h[(size_t)r * F_OUT + tx * 4] = *(float4*)&acc[i][0];
    }
}

// ---------------------------------------------------------------------------
// CSR build phase A: histogram of destination nodes.
// ---------------------------------------------------------------------------
__global__ __launch_bounds__(256) void hist_dst(
    const int* __restrict__ ei, int* __restrict__ cnt, int E)
{
    int e = blockIdx.x * 256 + threadIdx.x;
    if (e < E) atomicAdd(&cnt[ei[E + e]], 1);
}

// Phase B1: per-1024-chunk exclusive scan (Hillis-Steele in LDS).
__global__ __launch_bounds__(1024) void scan_chunks(
    const int* __restrict__ cnt, int* __restrict__ rowptr,
    int* __restrict__ bsum, int N)
{
    __shared__ int s[1024];
    int tid = threadIdx.x;
    int i   = blockIdx.x * 1024 + tid;
    int v   = (i < N) ? cnt[i] : 0;
    s[tid] = v;
    __syncthreads();
    #pragma unroll
    for (int off = 1; off < 1024; off <<= 1) {
        int t = (tid >= off) ? s[tid - off] : 0;
        __syncthreads();
        s[tid] += t;
        __syncthreads();
    }
    if (i < N) rowptr[i] = s[tid] - v;          // exclusive within chunk
    if (tid == 1023) bsum[blockIdx.x] = s[1023]; // chunk total
}

// Phase B2: scan the chunk totals (single wave, shfl scan). nb <= 64.
__global__ __launch_bounds__(64) void scan_bsums(int* __restrict__ bsum, int nb)
{
    int lane = threadIdx.x;
    int v = (lane < nb) ? bsum[lane] : 0;
    int orig = v;
    #pragma unroll
    for (int off = 1; off < 64; off <<= 1) {
        int t = __shfl_up(v, off);
        if (lane >= off) v += t;
    }
    if (lane < nb) bsum[lane] = v - orig;       // exclusive
}

// Phase B3: add chunk offsets; init cursor = rowptr; set rowptr[N] = E.
__global__ __launch_bounds__(1024) void scan_finish(
    int* __restrict__ rowptr, int* __restrict__ cursor,
    const int* __restrict__ bsum, int N, int E)
{
    int i = blockIdx.x * 1024 + threadIdx.x;
    if (i < N) {
        int r = rowptr[i] + bsum[i >> 10];
        rowptr[i] = r;
        cursor[i] = r;
    } else if (i == N) {
        rowptr[N] = E;
    }
}

// Phase C: fill buckets with packed (src, weight).
__global__ __launch_bounds__(256) void fill_buckets(
    const int* __restrict__ ei, const float* __restrict__ ew,
    int* __restrict__ cursor, uint2* __restrict__ bucket, int E)
{
    int e = blockIdx.x * 256 + threadIdx.x;
    if (e >= E) return;
    int   src = ei[e];
    int   dst = ei[E + e];
    float wgt = ew[e];
    int pos = atomicAdd(&cursor[dst], 1);
    uint2 b;
    b.x = (unsigned)src;
    b.y = __float_as_uint(wgt);
    bucket[pos] = b;
}

// ---------------------------------------------------------------------------
// Phase D: one wave per node. Lane l accumulates features [2l, 2l+1].
// 4-edge software pipeline: independent gathers issue together.
// Fused bias + relu epilogue; out written exactly once (no memset needed).
// ---------------------------------------------------------------------------
__global__ __launch_bounds__(256) void aggregate_csr(
    const float* __restrict__ h, const uint2* __restrict__ bucket,
    const int* __restrict__ rowptr, const float* __restrict__ bias,
    float* __restrict__ out, int N)
{
    int wave = threadIdx.x >> 6;
    int lane = threadIdx.x & 63;
    int n    = blockIdx.x * 4 + wave;
    if (n >= N) return;

    int start = rowptr[n];
    int end   = rowptr[n + 1];

    float2 acc = make_float2(0.f, 0.f);
    int i = start;
    for (; i + 4 <= end; i += 4) {
        uint2 b0 = bucket[i    ];
        uint2 b1 = bucket[i + 1];
        uint2 b2 = bucket[i + 2];
        uint2 b3 = bucket[i + 3];
        float2 h0 = *(const float2*)&h[(size_t)b0.x * F_OUT + lane * 2];
        float2 h1 = *(const float2*)&h[(size_t)b1.x * F_OUT + lane * 2];
        float2 h2 = *(const float2*)&h[(size_t)b2.x * F_OUT + lane * 2];
        float2 h3 = *(const float2*)&h[(size_t)b3.x * F_OUT + lane * 2];
        float w0 = __uint_as_float(b0.y), w1 = __uint_as_float(b1.y);
        float w2 = __uint_as_float(b2.y), w3 = __uint_as_float(b3.y);
        acc.x += h0.x * w0; acc.y += h0.y * w0;
        acc.x += h1.x * w1; acc.y += h1.y * w1;
        acc.x += h2.x * w2; acc.y += h2.y * w2;
        acc.x += h3.x * w3; acc.y += h3.y * w3;
    }
    for (; i < end; ++i) {
        uint2 b = bucket[i];
        float2 hv = *(const float2*)&h[(size_t)b.x * F_OUT + lane * 2];
        float wgt = __uint_as_float(b.y);
        acc.x += hv.x * wgt;
        acc.y += hv.y * wgt;
    }

    float2 bv = *(const float2*)&bias[lane * 2];
    float2 o;
    o.x = fmaxf(acc.x + bv.x, 0.f);
    o.y = fmaxf(acc.y + bv.y, 0.f);
    *(float2*)&out[(size_t)n * F_OUT + lane * 2] = o;
}

// ---------------------------------------------------------------------------
// Fallback kernels (atomic path) if workspace is too small for CSR.
// ---------------------------------------------------------------------------
__global__ __launch_bounds__(256) void scatter_atomic(
    const float* __restrict__ h, const int* __restrict__ ei,
    const float* __restrict__ ew, float* __restrict__ out, int E)
{
    long long gid = (long long)blockIdx.x * 256 + threadIdx.x;
    int e = (int)(gid >> 7);
    int f = (int)(gid & 127);
    if (e >= E) return;
    int   src = ei[e];
    int   dst = ei[E + e];
    float wgt = ew[e];
    float v   = h[(size_t)src * F_OUT + f] * wgt;
    atomicAdd(&out[(size_t)dst * F_OUT + f], v);
}

__global__ __launch_bounds__(256) void epilogue_bias_relu(
    float* __restrict__ out, const float* __restrict__ bias, int total)
{
    int i4 = (blockIdx.x * 256 + threadIdx.x) * 4;
    if (i4 >= total) return;
    float4 v = *(float4*)&out[i4];
    float4 b = *(const float4*)&bias[i4 & 127];
    v.x = fmaxf(v.x + b.x, 0.f);
    v.y = fmaxf(v.y + b.y, 0.f);
    v.z = fmaxf(v.z + b.z, 0.f);
    v.w = fmaxf(v.w + b.w, 0.f);
    *(float4*)&out[i4] = v;
}

static inline size_t align256(size_t x) { return (x + 255) & ~(size_t)255; }

extern "C" void kernel_launch(void* const* d_in, const int* in_sizes, int n_in,
                              void* d_out, int out_size, void* d_ws, size_t ws_size,
                              hipStream_t stream)
{
    const float* x    = (const float*)d_in[0];   // [N, 512]
    const int*   ei   = (const int*)  d_in[1];   // [2, E] int32
    const float* ew   = (const float*)d_in[2];   // [E]
    const float* w    = (const float*)d_in[3];   // [512, 128]
    const float* bias = (const float*)d_in[4];   // [128]
    float*       out  = (float*)d_out;           // [N, 128]

    const int N = in_sizes[0] / F_IN;            // 50000
    const int E = in_sizes[2];                   // 1600000

    // workspace layout
    char*  ws     = (char*)d_ws;
    size_t off    = 0;
    float* h      = (float*)(ws + off); off += align256((size_t)N * F_OUT * 4);
    int*   cnt    = (int*)  (ws + off); off += align256((size_t)N * 4);
    int*   rowptr = (int*)  (ws + off); off += align256((size_t)(N + 1) * 4);
    int*   cursor = (int*)  (ws + off); off += align256((size_t)N * 4);
    int*   bsum   = (int*)  (ws + off); off += 256;
    uint2* bucket = (uint2*)(ws + off); off += align256((size_t)E * 8);

    const int nb = (N + 1023) / 1024;            // scan chunks (49 for N=50000)

    if (off > ws_size || nb > 64) {
        // fallback: atomic scatter path (needs only h)
        hipMemsetAsync(d_out, 0, (size_t)out_size * sizeof(float), stream);
        gemm64x128<<<(N + 63) / 64, 256, 0, stream>>>(x, w, h, N);
        long long work = (long long)E * F_OUT;
        int sblocks = (int)((work + 255) / 256);
        scatter_atomic<<<sblocks, 256, 0, stream>>>(h, ei, ew, out, E);
        int total = N * F_OUT;
        epilogue_bias_relu<<<(total / 4 + 255) / 256, 256, 0, stream>>>(out, bias, total);
        return;
    }

    // CSR build
    hipMemsetAsync(cnt, 0, (size_t)N * 4, stream);
    hist_dst<<<(E + 255) / 256, 256, 0, stream>>>(ei, cnt, E);
    scan_chunks<<<nb, 1024, 0, stream>>>(cnt, rowptr, bsum, N);
    scan_bsums<<<1, 64, 0, stream>>>(bsum, nb);
    scan_finish<<<(N + 1024) / 1024, 1024, 0, stream>>>(rowptr, cursor, bsum, N, E);
    fill_buckets<<<(E + 255) / 256, 256, 0, stream>>>(ei, ew, cursor, bucket, E);

    // dense transform
    gemm64x128<<<(N + 63) / 64, 256, 0, stream>>>(x, w, h, N);

    // aggregate + fused epilogue
    aggregate_csr<<<(N + 3) / 4, 256, 0, stream>>>(h, bucket, rowptr, bias, out, N);
}

// Round 4
// 431.533 us; speedup vs baseline: 2.1467x; 1.2446x over previous
//
#include <hip/hip_runtime.h>

#define F_IN  512
#define F_OUT 128

typedef __attribute__((ext_vector_type(8))) short  short8;
typedef __attribute__((ext_vector_type(4))) float  floatx4;

__device__ __forceinline__ unsigned short f2bf(float f) {
    unsigned u = __float_as_uint(f);
    return (unsigned short)((u + 0x7FFF + ((u >> 16) & 1)) >> 16);  // RNE
}
__device__ __forceinline__ float bf2f(unsigned b) {
    return __uint_as_float(b << 16);
}

// ---------------------------------------------------------------------------
// One-time: w fp32 [512][128] -> wt bf16 [128][512] (n-major, k-contiguous).
// ---------------------------------------------------------------------------
__global__ __launch_bounds__(256) void convert_w(
    const float* __restrict__ w, unsigned short* __restrict__ wt)
{
    int gid = blockIdx.x * 256 + threadIdx.x;      // 65536 threads
    int n = gid >> 9, k = gid & 511;
    wt[gid] = f2bf(w[(size_t)k * F_OUT + n]);
}

// ---------------------------------------------------------------------------
// GEMM: h[N,128](bf16) = x[N,512](fp32->bf16) @ w, via mfma_f32_16x16x32_bf16.
// Block 256 = 4 waves; M_BLOCK=64 (wave = 16-row strip x 128 cols = 8 n-tiles).
// BK=64 per LDS stage (8 stages). LDS stride 68 elems: 8B-aligned b64 access,
// 2-way banks on frag reads (free per m136).
// ---------------------------------------------------------------------------
__global__ __launch_bounds__(256, 2) void gemm_mfma(
    const float* __restrict__ x, const unsigned short* __restrict__ wt,
    unsigned short* __restrict__ h, int N)
{
    __shared__ unsigned short sa[64 * 68];     // [row][k]
    __shared__ unsigned short sb[128 * 68];    // [n][k]

    const int tid  = threadIdx.x;
    const int wave = tid >> 6, lane = tid & 63;
    const int g    = lane >> 4, l16 = lane & 15;
    const int m0   = blockIdx.x * 64;

    // staging: x -> thread covers (row, 16-float quarter); wt -> (n, 32-elem half)
    const int arow = tid >> 2, aq = tid & 3;
    const int brow = tid >> 1, bh = tid & 1;

    floatx4 acc[8];
    #pragma unroll
    for (int i = 0; i < 8; ++i) acc[i] = (floatx4)(0.f);

    const bool  avalid = (m0 + arow) < N;
    const float* xp = x + (size_t)(m0 + arow) * F_IN + aq * 16;
    const unsigned short* bp = wt + brow * F_IN + bh * 32;

    float4 ax[4];
    uint4  bv[4];
    #pragma unroll
    for (int i = 0; i < 4; ++i) ax[i] = make_float4(0.f, 0.f, 0.f, 0.f);
    if (avalid) {
        #pragma unroll
        for (int i = 0; i < 4; ++i) ax[i] = ((const float4*)xp)[i];
    }
    #pragma unroll
    for (int i = 0; i < 4; ++i) bv[i] = ((const uint4*)bp)[i];

    for (int s = 0; s < 8; ++s) {
        __syncthreads();
        #pragma unroll
        for (int i = 0; i < 4; ++i) {
            ushort4 t;
            t.x = f2bf(ax[i].x); t.y = f2bf(ax[i].y);
            t.z = f2bf(ax[i].z); t.w = f2bf(ax[i].w);
            *(ushort4*)&sa[arow * 68 + aq * 16 + i * 4] = t;
        }
        #pragma unroll
        for (int i = 0; i < 4; ++i) {
            *(uint2*)&sb[brow * 68 + bh * 32 + i * 8]     = make_uint2(bv[i].x, bv[i].y);
            *(uint2*)&sb[brow * 68 + bh * 32 + i * 8 + 4] = make_uint2(bv[i].z, bv[i].w);
        }
        if (s < 7) {                       // prefetch next stage; overlaps MFMA below
            int k0n = (s + 1) * 64;
            if (avalid) {
                #pragma unroll
                for (int i = 0; i < 4; ++i) ax[i] = ((const float4*)(xp + k0n))[i];
            }
            #pragma unroll
            for (int i = 0; i < 4; ++i) bv[i] = ((const uint4*)(bp + k0n))[i];
        }
        __syncthreads();

        #pragma unroll
        for (int kc = 0; kc < 2; ++kc) {
            union { ushort4 u[2]; short8 v; } af;
            int abase = (wave * 16 + l16) * 68 + kc * 32 + g * 8;
            af.u[0] = *(ushort4*)&sa[abase];
            af.u[1] = *(ushort4*)&sa[abase + 4];
            #pragma unroll
            for (int nt = 0; nt < 8; ++nt) {
                union { ushort4 u[2]; short8 v; } bf;
                int bbase = (nt * 16 + l16) * 68 + kc * 32 + g * 8;
                bf.u[0] = *(ushort4*)&sb[bbase];
                bf.u[1] = *(ushort4*)&sb[bbase + 4];
                acc[nt] = __builtin_amdgcn_mfma_f32_16x16x32_bf16(af.v, bf.v, acc[nt], 0, 0, 0);
            }
        }
    }

    // epilogue: C/D layout col=l16, row=g*4+reg -> h bf16
    #pragma unroll
    for (int nt = 0; nt < 8; ++nt) {
        #pragma unroll
        for (int r = 0; r < 4; ++r) {
            int row = m0 + wave * 16 + g * 4 + r;
            if (row < N) h[(size_t)row * F_OUT + nt * 16 + l16] = f2bf(acc[nt][r]);
        }
    }
}

// ---------------------------------------------------------------------------
// CSR build: histogram -> scan -> bucket fill (packed 4B: src u16 | bf16 w).
// ---------------------------------------------------------------------------
__global__ __launch_bounds__(256) void hist_dst(
    const int* __restrict__ ei, int* __restrict__ cnt, int E)
{
    int e = blockIdx.x * 256 + threadIdx.x;
    if (e < E) atomicAdd(&cnt[ei[E + e]], 1);
}

__global__ __launch_bounds__(1024) void scan_chunks(
    const int* __restrict__ cnt, int* __restrict__ rowptr,
    int* __restrict__ bsum, int N)
{
    __shared__ int s[1024];
    int tid = threadIdx.x;
    int i   = blockIdx.x * 1024 + tid;
    int v   = (i < N) ? cnt[i] : 0;
    s[tid] = v;
    __syncthreads();
    #pragma unroll
    for (int off = 1; off < 1024; off <<= 1) {
        int t = (tid >= off) ? s[tid - off] : 0;
        __syncthreads();
        s[tid] += t;
        __syncthreads();
    }
    if (i < N) rowptr[i] = s[tid] - v;
    if (tid == 1023) bsum[blockIdx.x] = s[1023];
}

__global__ __launch_bounds__(64) void scan_bsums(int* __restrict__ bsum, int nb)
{
    int lane = threadIdx.x;
    int v = (lane < nb) ? bsum[lane] : 0;
    int orig = v;
    #pragma unroll
    for (int off = 1; off < 64; off <<= 1) {
        int t = __shfl_up(v, off);
        if (lane >= off) v += t;
    }
    if (lane < nb) bsum[lane] = v - orig;
}

__global__ __launch_bounds__(1024) void scan_finish(
    int* __restrict__ rowptr, int* __restrict__ cursor,
    const int* __restrict__ bsum, int N, int E)
{
    int i = blockIdx.x * 1024 + threadIdx.x;
    if (i < N) {
        int r = rowptr[i] + bsum[i >> 10];
        rowptr[i] = r;
        cursor[i] = r;
    } else if (i == N) {
        rowptr[N] = E;
    }
}

__global__ __launch_bounds__(256) void fill_buckets(
    const int* __restrict__ ei, const float* __restrict__ ew,
    int* __restrict__ cursor, unsigned* __restrict__ bucket, int E)
{
    int e = blockIdx.x * 256 + threadIdx.x;
    if (e >= E) return;
    int   src = ei[e];             // < 65536 (N = 50000)
    int   dst = ei[E + e];
    float wgt = ew[e];
    int pos = atomicAdd(&cursor[dst], 1);
    bucket[pos] = (unsigned)src | ((unsigned)f2bf(wgt) << 16);
}

// ---------------------------------------------------------------------------
// Aggregate: one wave per node, lane = 2 features (bf16 h, fp32 acc).
// Fused bias + relu; out written exactly once.
// ---------------------------------------------------------------------------
__global__ __launch_bounds__(256) void aggregate_csr(
    const unsigned short* __restrict__ h, const unsigned* __restrict__ bucket,
    const int* __restrict__ rowptr, const float* __restrict__ bias,
    float* __restrict__ out, int N)
{
    int wave = threadIdx.x >> 6;
    int lane = threadIdx.x & 63;
    int n    = blockIdx.x * 4 + wave;
    if (n >= N) return;

    int start = rowptr[n];
    int end   = rowptr[n + 1];

    float accx = 0.f, accy = 0.f;
    int i = start;
    for (; i + 4 <= end; i += 4) {
        unsigned b0 = bucket[i], b1 = bucket[i + 1], b2 = bucket[i + 2], b3 = bucket[i + 3];
        unsigned h0 = *(const unsigned*)&h[(size_t)(b0 & 0xFFFF) * F_OUT + lane * 2];
        unsigned h1 = *(const unsigned*)&h[(size_t)(b1 & 0xFFFF) * F_OUT + lane * 2];
        unsigned h2 = *(const unsigned*)&h[(size_t)(b2 & 0xFFFF) * F_OUT + lane * 2];
        unsigned h3 = *(const unsigned*)&h[(size_t)(b3 & 0xFFFF) * F_OUT + lane * 2];
        float w0 = bf2f(b0 >> 16), w1 = bf2f(b1 >> 16);
        float w2 = bf2f(b2 >> 16), w3 = bf2f(b3 >> 16);
        accx += bf2f(h0 & 0xFFFF) * w0; accy += bf2f(h0 >> 16) * w0;
        accx += bf2f(h1 & 0xFFFF) * w1; accy += bf2f(h1 >> 16) * w1;
        accx += bf2f(h2 & 0xFFFF) * w2; accy += bf2f(h2 >> 16) * w2;
        accx += bf2f(h3 & 0xFFFF) * w3; accy += bf2f(h3 >> 16) * w3;
    }
    for (; i < end; ++i) {
        unsigned b  = bucket[i];
        unsigned hv = *(const unsigned*)&h[(size_t)(b & 0xFFFF) * F_OUT + lane * 2];
        float wgt = bf2f(b >> 16);
        accx += bf2f(hv & 0xFFFF) * wgt;
        accy += bf2f(hv >> 16) * wgt;
    }

    float2 bv = *(const float2*)&bias[lane * 2];
    float2 o;
    o.x = fmaxf(accx + bv.x, 0.f);
    o.y = fmaxf(accy + bv.y, 0.f);
    *(float2*)&out[(size_t)n * F_OUT + lane * 2] = o;
}

static inline size_t align256(size_t x) { return (x + 255) & ~(size_t)255; }

extern "C" void kernel_launch(void* const* d_in, const int* in_sizes, int n_in,
                              void* d_out, int out_size, void* d_ws, size_t ws_size,
                              hipStream_t stream)
{
    const float* x    = (const float*)d_in[0];   // [N, 512]
    const int*   ei   = (const int*)  d_in[1];   // [2, E] int32
    const float* ew   = (const float*)d_in[2];   // [E]
    const float* w    = (const float*)d_in[3];   // [512, 128]
    const float* bias = (const float*)d_in[4];   // [128]
    float*       out  = (float*)d_out;           // [N, 128]

    const int N = in_sizes[0] / F_IN;            // 50000
    const int E = in_sizes[2];                   // 1600000

    // workspace layout (~19.5 MB)
    char*  ws = (char*)d_ws;
    size_t off = 0;
    unsigned short* h      = (unsigned short*)(ws + off); off += align256((size_t)N * F_OUT * 2);
    unsigned short* wt     = (unsigned short*)(ws + off); off += align256((size_t)F_OUT * F_IN * 2);
    int*            cnt    = (int*)(ws + off);            off += align256((size_t)N * 4);
    int*            rowptr = (int*)(ws + off);            off += align256((size_t)(N + 1) * 4);
    int*            cursor = (int*)(ws + off);            off += align256((size_t)N * 4);
    int*            bsum   = (int*)(ws + off);            off += 256;
    unsigned*       bucket = (unsigned*)(ws + off);       off += align256((size_t)E * 4);

    const int nb = (N + 1023) / 1024;            // 49 chunks

    // CSR build
    (void)hipMemsetAsync(cnt, 0, (size_t)N * 4, stream);
    hist_dst<<<(E + 255) / 256, 256, 0, stream>>>(ei, cnt, E);
    scan_chunks<<<nb, 1024, 0, stream>>>(cnt, rowptr, bsum, N);
    scan_bsums<<<1, 64, 0, stream>>>(bsum, nb);
    scan_finish<<<(N + 1024) / 1024, 1024, 0, stream>>>(rowptr, cursor, bsum, N, E);
    fill_buckets<<<(E + 255) / 256, 256, 0, stream>>>(ei, ew, cursor, bucket, E);

    // dense transform (bf16 MFMA)
    convert_w<<<(F_IN * F_OUT) / 256, 256, 0, stream>>>(w, wt);
    gemm_mfma<<<(N + 63) / 64, 256, 0, stream>>>(x, wt, h, N);

    // aggregate + fused epilogue
    aggregate_csr<<<(N + 3) / 4, 256, 0, stream>>>(h, bucket, rowptr, bias, out, N);
}